// Round 2
// baseline (211.892 us; speedup 1.0000x reference)
//
#include <hip/hip_runtime.h>
#include <cstddef>

#define B_ 2
#define NQ_ 10000
#define C_ 256
#define M_ 8
#define L_ 3
#define K_ 4
#define D_ 32
#define P_ 13125   // 10000 + 2500 + 625

typedef unsigned short u16;
typedef __attribute__((ext_vector_type(8))) short short8;
typedef __attribute__((ext_vector_type(4))) float f32x4;

static __device__ __forceinline__ u16 f2bf(float f) {
    union { float f; unsigned u; } x; x.f = f;
    unsigned r = x.u + 0x7fffu + ((x.u >> 16) & 1u);   // RNE
    return (u16)(r >> 16);
}
static __device__ __forceinline__ short8 cvt8(const float4& a, const float4& b) {
    short8 r;
    r[0] = (short)f2bf(a.x); r[1] = (short)f2bf(a.y);
    r[2] = (short)f2bf(a.z); r[3] = (short)f2bf(a.w);
    r[4] = (short)f2bf(b.x); r[5] = (short)f2bf(b.y);
    r[6] = (short)f2bf(b.z); r[7] = (short)f2bf(b.w);
    return r;
}

// ---------------------------------------------------------------------------
// f32 -> bf16 elementwise (query pre-convert). 8 elems/thread.
// ---------------------------------------------------------------------------
__global__ __launch_bounds__(256) void cvt_f32_bf16(
    const float* __restrict__ in, u16* __restrict__ out, int n8)
{
    const int i = blockIdx.x * 256 + threadIdx.x;
    if (i >= n8) return;
    const float4 a = *reinterpret_cast<const float4*>(in + (size_t)i * 8);
    const float4 b = *reinterpret_cast<const float4*>(in + (size_t)i * 8 + 4);
    *reinterpret_cast<short8*>(out + (size_t)i * 8) = cvt8(a, b);
}

// ---------------------------------------------------------------------------
// value [b][c][p] f32  ->  Vt [b][pixel][c] bf16 (pixel-major, level-offset)
// ---------------------------------------------------------------------------
__global__ __launch_bounds__(256) void transpose_value(
    const float* __restrict__ v0, const float* __restrict__ v1,
    const float* __restrict__ v2, u16* __restrict__ Vt)
{
    constexpr int HWs[3]  = {10000, 2500, 625};
    constexpr int offs[3] = {0, 10000, 12500};

    const int z   = blockIdx.z;
    const int b   = z / 3;
    const int lvl = z % 3;
    const int HW  = HWs[lvl];
    const int p0  = blockIdx.x * 64;
    if (p0 >= HW) return;
    const int c0  = blockIdx.y * 64;

    const float* V = (lvl == 0 ? v0 : (lvl == 1 ? v1 : v2)) + (size_t)b * 256 * HW;

    __shared__ u16 tile[64][66];
    const int t  = threadIdx.x;
    const int pl = t & 63;
    const int cb = t >> 6;   // 0..3

    #pragma unroll
    for (int i = 0; i < 16; ++i) {
        int c = cb + i * 4;
        float vv = 0.f;
        if (p0 + pl < HW)
            vv = V[(size_t)(c0 + c) * HW + p0 + pl];
        tile[pl][c] = f2bf(vv);
    }
    __syncthreads();

    const int cl = t & 63;
    const int pb = t >> 6;
    #pragma unroll
    for (int i = 0; i < 16; ++i) {
        int p = pb + i * 4;
        if (p0 + p < HW)
            Vt[((size_t)b * P_ + offs[lvl] + p0 + p) * 256 + c0 + cl] = tile[p][cl];
    }
}

// ---------------------------------------------------------------------------
// bf16 MFMA GEMM, XCD-aware 1-D grid, B staged from f32 with inline cvt.
// Cout[rows, Ntot] = A[rows,256] @ Bf[Ntot,256]^T + bias.
// Block tile 128 rows x 64 cols, 4 waves.
// ---------------------------------------------------------------------------
template <bool AF32, typename OutT>
__global__ __launch_bounds__(256) void gemm_panel(
    const void* __restrict__ Av, int rows, int nRowTiles, int npanel,
    const float* __restrict__ B1f, const float* __restrict__ bias1, int N1,
    const float* __restrict__ B2f, const float* __restrict__ bias2, int Ntot,
    OutT* __restrict__ Cout)
{
    __shared__ u16 Bs[64 * 264];

    const int bid  = blockIdx.x;
    const int rlo  = bid & 7;
    const int tmp  = bid >> 3;
    const int panel = tmp % npanel;
    const int rowTile = (tmp / npanel) * 8 + rlo;
    if (rowTile >= nRowTiles) return;

    const int t  = threadIdx.x;
    const int w  = t >> 6;
    const int l  = t & 63;
    const int row0 = rowTile * 128 + w * 32;
    const int o0   = panel * 64;
    const int lr = l & 15;
    const int kb = (l >> 4) * 8;

    // stage B panel: 64 cols x 256 k, f32 -> bf16
    #pragma unroll
    for (int i = 0; i < 8; ++i) {
        int idx = i * 256 + t;
        int col = idx >> 5;
        int kc  = (idx & 31) * 8;
        int colg = min(o0 + col, Ntot - 1);
        const float* Br = ((colg < N1) ? B1f + (size_t)colg * 256
                                       : B2f + (size_t)(colg - N1) * 256) + kc;
        float4 f0 = *reinterpret_cast<const float4*>(Br);
        float4 f1 = *reinterpret_cast<const float4*>(Br + 4);
        *reinterpret_cast<short8*>(&Bs[col * 264 + kc]) = cvt8(f0, f1);
    }

    const int ra0 = min(row0 + lr,      rows - 1);
    const int ra1 = min(row0 + 16 + lr, rows - 1);

    __syncthreads();

    f32x4 acc[2][4] = {};

    if constexpr (AF32) {
        const float* Af  = (const float*)Av;
        const float* Ap0 = Af + (size_t)ra0 * 256 + kb;
        const float* Ap1 = Af + (size_t)ra1 * 256 + kb;
        #pragma unroll
        for (int k0 = 0; k0 < 256; k0 += 32) {
            float4 x0 = *reinterpret_cast<const float4*>(Ap0 + k0);
            float4 y0 = *reinterpret_cast<const float4*>(Ap0 + k0 + 4);
            float4 x1 = *reinterpret_cast<const float4*>(Ap1 + k0);
            float4 y1 = *reinterpret_cast<const float4*>(Ap1 + k0 + 4);
            short8 a0 = cvt8(x0, y0);
            short8 a1 = cvt8(x1, y1);
            short8 b0 = *reinterpret_cast<const short8*>(&Bs[(0 * 16 + lr) * 264 + kb + k0]);
            short8 b1 = *reinterpret_cast<const short8*>(&Bs[(1 * 16 + lr) * 264 + kb + k0]);
            short8 b2 = *reinterpret_cast<const short8*>(&Bs[(2 * 16 + lr) * 264 + kb + k0]);
            short8 b3 = *reinterpret_cast<const short8*>(&Bs[(3 * 16 + lr) * 264 + kb + k0]);
            acc[0][0] = __builtin_amdgcn_mfma_f32_16x16x32_bf16(a0, b0, acc[0][0], 0, 0, 0);
            acc[0][1] = __builtin_amdgcn_mfma_f32_16x16x32_bf16(a0, b1, acc[0][1], 0, 0, 0);
            acc[0][2] = __builtin_amdgcn_mfma_f32_16x16x32_bf16(a0, b2, acc[0][2], 0, 0, 0);
            acc[0][3] = __builtin_amdgcn_mfma_f32_16x16x32_bf16(a0, b3, acc[0][3], 0, 0, 0);
            acc[1][0] = __builtin_amdgcn_mfma_f32_16x16x32_bf16(a1, b0, acc[1][0], 0, 0, 0);
            acc[1][1] = __builtin_amdgcn_mfma_f32_16x16x32_bf16(a1, b1, acc[1][1], 0, 0, 0);
            acc[1][2] = __builtin_amdgcn_mfma_f32_16x16x32_bf16(a1, b2, acc[1][2], 0, 0, 0);
            acc[1][3] = __builtin_amdgcn_mfma_f32_16x16x32_bf16(a1, b3, acc[1][3], 0, 0, 0);
        }
    } else {
        const u16* Af  = (const u16*)Av;
        const u16* Ap0 = Af + (size_t)ra0 * 256 + kb;
        const u16* Ap1 = Af + (size_t)ra1 * 256 + kb;
        #pragma unroll
        for (int k0 = 0; k0 < 256; k0 += 32) {
            short8 a0 = *reinterpret_cast<const short8*>(Ap0 + k0);
            short8 a1 = *reinterpret_cast<const short8*>(Ap1 + k0);
            short8 b0 = *reinterpret_cast<const short8*>(&Bs[(0 * 16 + lr) * 264 + kb + k0]);
            short8 b1 = *reinterpret_cast<const short8*>(&Bs[(1 * 16 + lr) * 264 + kb + k0]);
            short8 b2 = *reinterpret_cast<const short8*>(&Bs[(2 * 16 + lr) * 264 + kb + k0]);
            short8 b3 = *reinterpret_cast<const short8*>(&Bs[(3 * 16 + lr) * 264 + kb + k0]);
            acc[0][0] = __builtin_amdgcn_mfma_f32_16x16x32_bf16(a0, b0, acc[0][0], 0, 0, 0);
            acc[0][1] = __builtin_amdgcn_mfma_f32_16x16x32_bf16(a0, b1, acc[0][1], 0, 0, 0);
            acc[0][2] = __builtin_amdgcn_mfma_f32_16x16x32_bf16(a0, b2, acc[0][2], 0, 0, 0);
            acc[0][3] = __builtin_amdgcn_mfma_f32_16x16x32_bf16(a0, b3, acc[0][3], 0, 0, 0);
            acc[1][0] = __builtin_amdgcn_mfma_f32_16x16x32_bf16(a1, b0, acc[1][0], 0, 0, 0);
            acc[1][1] = __builtin_amdgcn_mfma_f32_16x16x32_bf16(a1, b1, acc[1][1], 0, 0, 0);
            acc[1][2] = __builtin_amdgcn_mfma_f32_16x16x32_bf16(a1, b2, acc[1][2], 0, 0, 0);
            acc[1][3] = __builtin_amdgcn_mfma_f32_16x16x32_bf16(a1, b3, acc[1][3], 0, 0, 0);
        }
    }

    // C/D layout: col = l&15, row = (l>>4)*4 + reg  [m89-verified]
    const int orow = (l >> 4) * 4;
    #pragma unroll
    for (int ct = 0; ct < 4; ++ct) {
        const int col = o0 + ct * 16 + lr;
        if (col >= Ntot) continue;
        const float bsv = (col < N1) ? bias1[col] : bias2[col - N1];
        #pragma unroll
        for (int rt = 0; rt < 2; ++rt) {
            #pragma unroll
            for (int r = 0; r < 4; ++r) {
                const int row = row0 + rt * 16 + orow + r;
                if (row < rows) {
                    float val = acc[rt][ct][r] + bsv;
                    if constexpr (sizeof(OutT) == 2)
                        Cout[(size_t)row * Ntot + col] = (OutT)f2bf(val);
                    else
                        Cout[(size_t)row * Ntot + col] = (OutT)val;
                }
            }
        }
    }
}

// ---------------------------------------------------------------------------
// Sampling v2: 4 queries/block, 4 channels/thread (uint2 loads), depth-4
// software-pipelined gather ring (static indices under full unroll).
// Phase 1: 384 jobs (q,m,j) on 256 threads -> softmax weight + 4 corner
// indices + premultiplied bilinear weights in LDS.
// Phase 2: thread = (q = t>>6, head = (t&63)>>3, chanquad = t&7).
// ---------------------------------------------------------------------------
__global__ __launch_bounds__(256) void sample_kernel(
    const float* __restrict__ S,       // [B*NQ, 288]
    const float* __restrict__ refp,    // [B*NQ, 2]
    const u16* __restrict__ proj,      // [B, P_, 256] bf16
    u16* __restrict__ out2)            // [B*NQ, 256] bf16
{
    constexpr int Wd[3]   = {100, 50, 25};
    constexpr int offs[3] = {0, 10000, 12500};

    __shared__ int   midx[384][4];
    __shared__ float mw[384][4];

    const int t = threadIdx.x;

    for (int job = t; job < 384; job += 256) {
        const int q  = job / 96;
        const int tq = job % 96;
        const int tm = tq / 12;      // head
        const int tj = tq % 12;      // point = l*4+k
        const int bq = blockIdx.x * 4 + q;
        const float* Sq = S + (size_t)bq * 288;

        float lg[12], mx = -1e30f;
        #pragma unroll
        for (int jj = 0; jj < 12; ++jj) {
            lg[jj] = Sq[192 + tm * 12 + jj];
            mx = fmaxf(mx, lg[jj]);
        }
        float sum = 0.f;
        #pragma unroll
        for (int jj = 0; jj < 12; ++jj) sum += __expf(lg[jj] - mx);
        const float attn = __expf(lg[tj] - mx) / sum;

        const int l  = tj >> 2;
        const int Wl = Wd[l];
        const float refx = refp[(size_t)bq * 2 + 0];
        const float refy = refp[(size_t)bq * 2 + 1];
        const float ox = Sq[(tm * 12 + tj) * 2 + 0];
        const float oy = Sq[(tm * 12 + tj) * 2 + 1];
        const float px = refx * (float)Wl + ox - 0.5f;   // H==W per level
        const float py = refy * (float)Wl + oy - 0.5f;
        const float x0f = floorf(px), y0f = floorf(py);
        const float wx1 = px - x0f, wy1 = py - y0f;
        const float wx0 = 1.f - wx1, wy0 = 1.f - wy1;
        const int x0 = (int)x0f, y0 = (int)y0f;
        const int x1 = x0 + 1, y1 = y0 + 1;
        const bool vx0 = (unsigned)x0 < (unsigned)Wl;
        const bool vx1 = (unsigned)x1 < (unsigned)Wl;
        const bool vy0 = (unsigned)y0 < (unsigned)Wl;
        const bool vy1 = (unsigned)y1 < (unsigned)Wl;
        const int chb  = tm * 32;
        const int base = offs[l];
        midx[job][0] = (vx0 && vy0) ? ((base + y0 * Wl + x0) * 256 + chb) : 0;
        midx[job][1] = (vx1 && vy0) ? ((base + y0 * Wl + x1) * 256 + chb) : 0;
        midx[job][2] = (vx0 && vy1) ? ((base + y1 * Wl + x0) * 256 + chb) : 0;
        midx[job][3] = (vx1 && vy1) ? ((base + y1 * Wl + x1) * 256 + chb) : 0;
        mw[job][0] = (vx0 && vy0) ? attn * wx0 * wy0 : 0.f;
        mw[job][1] = (vx1 && vy0) ? attn * wx1 * wy0 : 0.f;
        mw[job][2] = (vx0 && vy1) ? attn * wx0 * wy1 : 0.f;
        mw[job][3] = (vx1 && vy1) ? attn * wx1 * wy1 : 0.f;
    }
    __syncthreads();

    const int qi  = t >> 6;          // query within block
    const int tt  = t & 63;
    const int mh  = tt >> 3;         // head 0..7
    const int d8  = tt & 7;          // channel quad 0..7
    const int bq2 = blockIdx.x * 4 + qi;
    const int b   = bq2 / NQ_;
    const u16* projb = proj + (size_t)b * P_ * 256 + 4 * d8;
    const int base_mj = qi * 96 + mh * 12;

    float acc0 = 0.f, acc1 = 0.f, acc2 = 0.f, acc3 = 0.f;

    uint2 v[4][4];   // [pipeline stage][corner] — static idx under full unroll
    int4  o_[4];

    #pragma unroll
    for (int js = 0; js < 3; ++js) {
        o_[js] = *reinterpret_cast<const int4*>(midx[base_mj + js]);
        v[js][0] = *reinterpret_cast<const uint2*>(projb + o_[js].x);
        v[js][1] = *reinterpret_cast<const uint2*>(projb + o_[js].y);
        v[js][2] = *reinterpret_cast<const uint2*>(projb + o_[js].z);
        v[js][3] = *reinterpret_cast<const uint2*>(projb + o_[js].w);
    }

    #pragma unroll
    for (int j = 0; j < 12; ++j) {
        const int s = j & 3;
        if (j + 3 < 12) {
            const int s3 = (j + 3) & 3;
            o_[s3] = *reinterpret_cast<const int4*>(midx[base_mj + j + 3]);
            v[s3][0] = *reinterpret_cast<const uint2*>(projb + o_[s3].x);
            v[s3][1] = *reinterpret_cast<const uint2*>(projb + o_[s3].y);
            v[s3][2] = *reinterpret_cast<const uint2*>(projb + o_[s3].z);
            v[s3][3] = *reinterpret_cast<const uint2*>(projb + o_[s3].w);
        }
        const float4 ww = *reinterpret_cast<const float4*>(mw[base_mj + j]);
        #pragma unroll
        for (int c = 0; c < 4; ++c) {
            const unsigned ux = v[s][c].x;
            const unsigned uy = v[s][c].y;
            const float wc = (c == 0) ? ww.x : (c == 1) ? ww.y : (c == 2) ? ww.z : ww.w;
            union { unsigned u; float f; } e0, e1, e2, e3;
            e0.u = ux << 16; e1.u = ux & 0xffff0000u;
            e2.u = uy << 16; e3.u = uy & 0xffff0000u;
            acc0 = fmaf(wc, e0.f, acc0);
            acc1 = fmaf(wc, e1.f, acc1);
            acc2 = fmaf(wc, e2.f, acc2);
            acc3 = fmaf(wc, e3.f, acc3);
        }
    }

    uint2 st;
    st.x = (unsigned)f2bf(acc0) | ((unsigned)f2bf(acc1) << 16);
    st.y = (unsigned)f2bf(acc2) | ((unsigned)f2bf(acc3) << 16);
    *reinterpret_cast<uint2*>(out2 + (size_t)bq2 * 256 + mh * 32 + d8 * 4) = st;
}

// ---------------------------------------------------------------------------
extern "C" void kernel_launch(void* const* d_in, const int* in_sizes, int n_in,
                              void* d_out, int out_size, void* d_ws, size_t ws_size,
                              hipStream_t stream)
{
    const float* query = (const float*)d_in[0];
    const float* refp  = (const float*)d_in[1];
    const float* v0    = (const float*)d_in[2];
    const float* v1    = (const float*)d_in[3];
    const float* v2    = (const float*)d_in[4];
    const float* Wv    = (const float*)d_in[5];
    const float* bv    = (const float*)d_in[6];
    const float* Ws    = (const float*)d_in[7];
    const float* bs    = (const float*)d_in[8];
    const float* Wa    = (const float*)d_in[9];
    const float* ba    = (const float*)d_in[10];
    const float* Wo    = (const float*)d_in[11];
    const float* bo    = (const float*)d_in[12];
    float* out = (float*)d_out;

    char* wsb = (char*)d_ws;
    u16*   proj  = (u16*)wsb;    wsb += (size_t)B_ * P_ * 256 * 2;   // 13.44 MB
    float* S     = (float*)wsb;  wsb += (size_t)B_ * NQ_ * 288 * 4;  // 23.04 MB
    u16*   Vt    = (u16*)wsb;    wsb += (size_t)B_ * P_ * 256 * 2;   // 13.44 MB
    u16*   out2  = (u16*)wsb;    wsb += (size_t)B_ * NQ_ * 256 * 2;  // 10.24 MB
    u16*   qbf   = (u16*)wsb;    wsb += (size_t)B_ * NQ_ * 256 * 2;  // 10.24 MB

    dim3 blk(256);

    // 0a) query f32 -> bf16 (5.12M elems, 8/thread)
    cvt_f32_bf16<<<dim3(2500), blk, 0, stream>>>(query, qbf, 640000);

    // 0b) value transpose+cvt -> Vt bf16 [b][pixel][c]
    transpose_value<<<dim3(157, 4, 6), blk, 0, stream>>>(v0, v1, v2, Vt);

    // 1) value projection -> proj bf16.  nRowTiles=206, npanel=4 -> 26*4*8
    gemm_panel<false, u16><<<dim3(832), blk, 0, stream>>>(
        Vt, B_ * P_, 206, 4, Wv, bv, 256, Wv, bv, 256, proj);

    // 2) offsets+logits -> S f32 (bf16 A path).  nRowTiles=157, npanel=5
    gemm_panel<false, float><<<dim3(800), blk, 0, stream>>>(
        qbf, B_ * NQ_, 157, 5, Ws, bs, 192, Wa, ba, 288, S);

    // 3) softmax + bilinear sampling -> out2 bf16 (4 queries / block)
    sample_kernel<<<dim3(5000), blk, 0, stream>>>(S, refp, proj, out2);

    // 4) output projection -> d_out f32.  nRowTiles=157, npanel=4 -> 20*4*8
    gemm_panel<false, float><<<dim3(640), blk, 0, stream>>>(
        out2, B_ * NQ_, 157, 4, Wo, bo, 256, Wo, bo, 256, out);
}

// Round 4
// 201.079 us; speedup vs baseline: 1.0538x; 1.0538x over previous
//
#include <hip/hip_runtime.h>
#include <cstddef>

#define B_ 2
#define NQ_ 10000
#define C_ 256
#define M_ 8
#define L_ 3
#define K_ 4
#define D_ 32
#define P_ 13125   // 10000 + 2500 + 625

typedef unsigned short u16;
typedef __attribute__((ext_vector_type(8))) short short8;
typedef __attribute__((ext_vector_type(4))) float f32x4;

static __device__ __forceinline__ u16 f2bf(float f) {
    union { float f; unsigned u; } x; x.f = f;
    unsigned r = x.u + 0x7fffu + ((x.u >> 16) & 1u);   // RNE
    return (u16)(r >> 16);
}
static __device__ __forceinline__ short8 cvt8(const float4& a, const float4& b) {
    short8 r;
    r[0] = (short)f2bf(a.x); r[1] = (short)f2bf(a.y);
    r[2] = (short)f2bf(a.z); r[3] = (short)f2bf(a.w);
    r[4] = (short)f2bf(b.x); r[5] = (short)f2bf(b.y);
    r[6] = (short)f2bf(b.z); r[7] = (short)f2bf(b.w);
    return r;
}

// ---------------------------------------------------------------------------
// Weight pre-convert f32 -> bf16, all four matrices in ONE launch.
// Layout in wb: Wv @ 0 (65536), Ws @ 65536 (49152), Wa @ 114688 (24576),
//               Wo @ 139264 (65536). Total 204800 elems = 25600 chunks of 8.
// ---------------------------------------------------------------------------
__global__ __launch_bounds__(256) void cvt_weights(
    const float* __restrict__ Wv, const float* __restrict__ Ws,
    const float* __restrict__ Wa, const float* __restrict__ Wo,
    u16* __restrict__ wb)
{
    const int i = blockIdx.x * 256 + threadIdx.x;
    if (i >= 25600) return;
    const int g = i * 8;
    const float* src;
    if (g < 65536)       src = Wv + g;
    else if (g < 114688) src = Ws + (g - 65536);
    else if (g < 139264) src = Wa + (g - 114688);
    else                 src = Wo + (g - 139264);
    const float4 a = *reinterpret_cast<const float4*>(src);
    const float4 b = *reinterpret_cast<const float4*>(src + 4);
    *reinterpret_cast<short8*>(wb + g) = cvt8(a, b);
}

// ---------------------------------------------------------------------------
// value [b][c][p] f32  ->  Vt [b][pixel][c] bf16 (pixel-major, level-offset)
// ---------------------------------------------------------------------------
__global__ __launch_bounds__(256) void transpose_value(
    const float* __restrict__ v0, const float* __restrict__ v1,
    const float* __restrict__ v2, u16* __restrict__ Vt)
{
    constexpr int HWs[3]  = {10000, 2500, 625};
    constexpr int offs[3] = {0, 10000, 12500};

    const int z   = blockIdx.z;
    const int b   = z / 3;
    const int lvl = z % 3;
    const int HW  = HWs[lvl];
    const int p0  = blockIdx.x * 64;
    if (p0 >= HW) return;
    const int c0  = blockIdx.y * 64;

    const float* V = (lvl == 0 ? v0 : (lvl == 1 ? v1 : v2)) + (size_t)b * 256 * HW;

    __shared__ u16 tile[64][66];
    const int t  = threadIdx.x;
    const int pl = t & 63;
    const int cb = t >> 6;   // 0..3

    #pragma unroll
    for (int i = 0; i < 16; ++i) {
        int c = cb + i * 4;
        float vv = 0.f;
        if (p0 + pl < HW)
            vv = V[(size_t)(c0 + c) * HW + p0 + pl];
        tile[pl][c] = f2bf(vv);
    }
    __syncthreads();

    const int cl = t & 63;
    const int pb = t >> 6;
    #pragma unroll
    for (int i = 0; i < 16; ++i) {
        int p = pb + i * 4;
        if (p0 + p < HW)
            Vt[((size_t)b * P_ + offs[lvl] + p0 + p) * 256 + c0 + cl] = tile[p][cl];
    }
}

// ---------------------------------------------------------------------------
// bf16 MFMA GEMM, XCD-aware 1-D grid, B staged from PRE-CONVERTED bf16.
// Cout[rows, Ntot] = A[rows,256] @ Bb[Ntot,256]^T + bias.
// bid = (rhi*npanel + panel)*8 + rlo; rowTile = rhi*8+rlo -> panel-blocks
// sharing a row stripe are 8 apart (same XCD slot, adjacent in time) so
// A re-reads across panels hit L2. Block tile 128 rows x 64 cols, 4 waves.
// ---------------------------------------------------------------------------
template <bool AF32, typename OutT>
__global__ __launch_bounds__(256) void gemm_panel(
    const void* __restrict__ Av, int rows, int nRowTiles, int npanel,
    const u16* __restrict__ B1b, const float* __restrict__ bias1, int N1,
    const u16* __restrict__ B2b, const float* __restrict__ bias2, int Ntot,
    OutT* __restrict__ Cout)
{
    __shared__ u16 Bs[64 * 264];

    const int bid  = blockIdx.x;
    const int rlo  = bid & 7;
    const int tmp  = bid >> 3;
    const int panel = tmp % npanel;
    const int rowTile = (tmp / npanel) * 8 + rlo;
    if (rowTile >= nRowTiles) return;

    const int t  = threadIdx.x;
    const int w  = t >> 6;
    const int l  = t & 63;
    const int row0 = rowTile * 128 + w * 32;
    const int o0   = panel * 64;
    const int lr = l & 15;
    const int kb = (l >> 4) * 8;

    // stage B panel: 64 cols x 256 k, bf16 direct (16B per thread-iter)
    #pragma unroll
    for (int i = 0; i < 8; ++i) {
        int idx = i * 256 + t;
        int col = idx >> 5;
        int kc  = (idx & 31) * 8;
        int colg = min(o0 + col, Ntot - 1);
        const u16* Br = ((colg < N1) ? B1b + (size_t)colg * 256
                                     : B2b + (size_t)(colg - N1) * 256) + kc;
        *reinterpret_cast<short8*>(&Bs[col * 264 + kc]) =
            *reinterpret_cast<const short8*>(Br);
    }

    const int ra0 = min(row0 + lr,      rows - 1);
    const int ra1 = min(row0 + 16 + lr, rows - 1);

    __syncthreads();

    f32x4 acc[2][4] = {};

    if constexpr (AF32) {
        const float* Af  = (const float*)Av;
        const float* Ap0 = Af + (size_t)ra0 * 256 + kb;
        const float* Ap1 = Af + (size_t)ra1 * 256 + kb;
        #pragma unroll
        for (int k0 = 0; k0 < 256; k0 += 32) {
            float4 x0 = *reinterpret_cast<const float4*>(Ap0 + k0);
            float4 y0 = *reinterpret_cast<const float4*>(Ap0 + k0 + 4);
            float4 x1 = *reinterpret_cast<const float4*>(Ap1 + k0);
            float4 y1 = *reinterpret_cast<const float4*>(Ap1 + k0 + 4);
            short8 a0 = cvt8(x0, y0);
            short8 a1 = cvt8(x1, y1);
            short8 b0 = *reinterpret_cast<const short8*>(&Bs[(0 * 16 + lr) * 264 + kb + k0]);
            short8 b1 = *reinterpret_cast<const short8*>(&Bs[(1 * 16 + lr) * 264 + kb + k0]);
            short8 b2 = *reinterpret_cast<const short8*>(&Bs[(2 * 16 + lr) * 264 + kb + k0]);
            short8 b3 = *reinterpret_cast<const short8*>(&Bs[(3 * 16 + lr) * 264 + kb + k0]);
            acc[0][0] = __builtin_amdgcn_mfma_f32_16x16x32_bf16(a0, b0, acc[0][0], 0, 0, 0);
            acc[0][1] = __builtin_amdgcn_mfma_f32_16x16x32_bf16(a0, b1, acc[0][1], 0, 0, 0);
            acc[0][2] = __builtin_amdgcn_mfma_f32_16x16x32_bf16(a0, b2, acc[0][2], 0, 0, 0);
            acc[0][3] = __builtin_amdgcn_mfma_f32_16x16x32_bf16(a0, b3, acc[0][3], 0, 0, 0);
            acc[1][0] = __builtin_amdgcn_mfma_f32_16x16x32_bf16(a1, b0, acc[1][0], 0, 0, 0);
            acc[1][1] = __builtin_amdgcn_mfma_f32_16x16x32_bf16(a1, b1, acc[1][1], 0, 0, 0);
            acc[1][2] = __builtin_amdgcn_mfma_f32_16x16x32_bf16(a1, b2, acc[1][2], 0, 0, 0);
            acc[1][3] = __builtin_amdgcn_mfma_f32_16x16x32_bf16(a1, b3, acc[1][3], 0, 0, 0);
        }
    } else {
        const u16* Af  = (const u16*)Av;
        const u16* Ap0 = Af + (size_t)ra0 * 256 + kb;
        const u16* Ap1 = Af + (size_t)ra1 * 256 + kb;
        #pragma unroll
        for (int k0 = 0; k0 < 256; k0 += 32) {
            short8 a0 = *reinterpret_cast<const short8*>(Ap0 + k0);
            short8 a1 = *reinterpret_cast<const short8*>(Ap1 + k0);
            short8 b0 = *reinterpret_cast<const short8*>(&Bs[(0 * 16 + lr) * 264 + kb + k0]);
            short8 b1 = *reinterpret_cast<const short8*>(&Bs[(1 * 16 + lr) * 264 + kb + k0]);
            short8 b2 = *reinterpret_cast<const short8*>(&Bs[(2 * 16 + lr) * 264 + kb + k0]);
            short8 b3 = *reinterpret_cast<const short8*>(&Bs[(3 * 16 + lr) * 264 + kb + k0]);
            acc[0][0] = __builtin_amdgcn_mfma_f32_16x16x32_bf16(a0, b0, acc[0][0], 0, 0, 0);
            acc[0][1] = __builtin_amdgcn_mfma_f32_16x16x32_bf16(a0, b1, acc[0][1], 0, 0, 0);
            acc[0][2] = __builtin_amdgcn_mfma_f32_16x16x32_bf16(a0, b2, acc[0][2], 0, 0, 0);
            acc[0][3] = __builtin_amdgcn_mfma_f32_16x16x32_bf16(a0, b3, acc[0][3], 0, 0, 0);
            acc[1][0] = __builtin_amdgcn_mfma_f32_16x16x32_bf16(a1, b0, acc[1][0], 0, 0, 0);
            acc[1][1] = __builtin_amdgcn_mfma_f32_16x16x32_bf16(a1, b1, acc[1][1], 0, 0, 0);
            acc[1][2] = __builtin_amdgcn_mfma_f32_16x16x32_bf16(a1, b2, acc[1][2], 0, 0, 0);
            acc[1][3] = __builtin_amdgcn_mfma_f32_16x16x32_bf16(a1, b3, acc[1][3], 0, 0, 0);
        }
    }

    // C/D layout: col = l&15, row = (l>>4)*4 + reg  [m89-verified]
    const int orow = (l >> 4) * 4;
    #pragma unroll
    for (int ct = 0; ct < 4; ++ct) {
        const int col = o0 + ct * 16 + lr;
        if (col >= Ntot) continue;
        const float bsv = (col < N1) ? bias1[col] : bias2[col - N1];
        #pragma unroll
        for (int rt = 0; rt < 2; ++rt) {
            #pragma unroll
            for (int r = 0; r < 4; ++r) {
                const int row = row0 + rt * 16 + orow + r;
                if (row < rows) {
                    float val = acc[rt][ct][r] + bsv;
                    if constexpr (sizeof(OutT) == 2)
                        Cout[(size_t)row * Ntot + col] = (OutT)f2bf(val);
                    else
                        Cout[(size_t)row * Ntot + col] = (OutT)val;
                }
            }
        }
    }
}

// ---------------------------------------------------------------------------
// Sampling (round-1 proven version): 2 queries/block, 2 channels/thread.
// Phase 1 (threads 0..191): per (query q, head m, point j) softmax weight +
// 4 corner indices + premultiplied bilinear weights -> LDS.
// Phase 2: thread = (q = t>>7, head = (t&127)>>4, chanpair = t&15).
// ---------------------------------------------------------------------------
__global__ __launch_bounds__(256) void sample_kernel(
    const float* __restrict__ S,       // [B*NQ, 288]
    const float* __restrict__ refp,    // [B*NQ, 2]
    const u16* __restrict__ proj,      // [B, P_, 256] bf16
    u16* __restrict__ out2)            // [B*NQ, 256] bf16
{
    constexpr int Wd[3]   = {100, 50, 25};
    constexpr int offs[3] = {0, 10000, 12500};

    __shared__ int   midx[192][4];
    __shared__ float mw[192][4];

    const int t = threadIdx.x;

    if (t < 192) {
        const int q  = t / 96;
        const int tq = t % 96;
        const int tm = tq / 12;      // head
        const int tj = tq % 12;      // point = l*4+k
        const int bq = blockIdx.x * 2 + q;
        const float* Sq = S + (size_t)bq * 288;

        float lg[12], mx = -1e30f;
        #pragma unroll
        for (int jj = 0; jj < 12; ++jj) {
            lg[jj] = Sq[192 + tm * 12 + jj];
            mx = fmaxf(mx, lg[jj]);
        }
        float sum = 0.f;
        #pragma unroll
        for (int jj = 0; jj < 12; ++jj) sum += __expf(lg[jj] - mx);
        const float attn = __expf(lg[tj] - mx) / sum;

        const int l  = tj >> 2;
        const int Wl = Wd[l];
        const float refx = refp[(size_t)bq * 2 + 0];
        const float refy = refp[(size_t)bq * 2 + 1];
        const float ox = Sq[(tm * 12 + tj) * 2 + 0];
        const float oy = Sq[(tm * 12 + tj) * 2 + 1];
        const float px = refx * (float)Wl + ox - 0.5f;   // H==W per level
        const float py = refy * (float)Wl + oy - 0.5f;
        const float x0f = floorf(px), y0f = floorf(py);
        const float wx1 = px - x0f, wy1 = py - y0f;
        const float wx0 = 1.f - wx1, wy0 = 1.f - wy1;
        const int x0 = (int)x0f, y0 = (int)y0f;
        const int x1 = x0 + 1, y1 = y0 + 1;
        const bool vx0 = (unsigned)x0 < (unsigned)Wl;
        const bool vx1 = (unsigned)x1 < (unsigned)Wl;
        const bool vy0 = (unsigned)y0 < (unsigned)Wl;
        const bool vy1 = (unsigned)y1 < (unsigned)Wl;
        const int chb  = tm * 32;
        const int base = offs[l];
        midx[t][0] = (vx0 && vy0) ? ((base + y0 * Wl + x0) * 256 + chb) : 0;
        midx[t][1] = (vx1 && vy0) ? ((base + y0 * Wl + x1) * 256 + chb) : 0;
        midx[t][2] = (vx0 && vy1) ? ((base + y1 * Wl + x0) * 256 + chb) : 0;
        midx[t][3] = (vx1 && vy1) ? ((base + y1 * Wl + x1) * 256 + chb) : 0;
        mw[t][0] = (vx0 && vy0) ? attn * wx0 * wy0 : 0.f;
        mw[t][1] = (vx1 && vy0) ? attn * wx1 * wy0 : 0.f;
        mw[t][2] = (vx0 && vy1) ? attn * wx0 * wy1 : 0.f;
        mw[t][3] = (vx1 && vy1) ? attn * wx1 * wy1 : 0.f;
    }
    __syncthreads();

    const int qi  = t >> 7;
    const int tt  = t & 127;
    const int mh  = tt >> 4;
    const int d16 = tt & 15;
    const int bq2 = blockIdx.x * 2 + qi;
    const int b   = bq2 / NQ_;
    const u16* projb = proj + (size_t)b * P_ * 256 + 2 * d16;

    float acc0 = 0.f, acc1 = 0.f;

    #pragma unroll
    for (int j = 0; j < 12; ++j) {
        const int mj = qi * 96 + mh * 12 + j;
        const int4   o  = *reinterpret_cast<const int4*>(midx[mj]);
        const float4 ww = *reinterpret_cast<const float4*>(mw[mj]);
        const unsigned u00 = *reinterpret_cast<const unsigned*>(projb + o.x);
        const unsigned u10 = *reinterpret_cast<const unsigned*>(projb + o.y);
        const unsigned u01 = *reinterpret_cast<const unsigned*>(projb + o.z);
        const unsigned u11 = *reinterpret_cast<const unsigned*>(projb + o.w);
        union { unsigned u; float f; } c0, c1;
        c0.u = u00 << 16;          c1.u = u00 & 0xffff0000u;
        acc0 = fmaf(ww.x, c0.f, acc0); acc1 = fmaf(ww.x, c1.f, acc1);
        c0.u = u10 << 16;          c1.u = u10 & 0xffff0000u;
        acc0 = fmaf(ww.y, c0.f, acc0); acc1 = fmaf(ww.y, c1.f, acc1);
        c0.u = u01 << 16;          c1.u = u01 & 0xffff0000u;
        acc0 = fmaf(ww.z, c0.f, acc0); acc1 = fmaf(ww.z, c1.f, acc1);
        c0.u = u11 << 16;          c1.u = u11 & 0xffff0000u;
        acc0 = fmaf(ww.w, c0.f, acc0); acc1 = fmaf(ww.w, c1.f, acc1);
    }

    const unsigned packed = (unsigned)f2bf(acc0) | ((unsigned)f2bf(acc1) << 16);
    *reinterpret_cast<unsigned*>(out2 + (size_t)bq2 * 256 + mh * 32 + 2 * d16) = packed;
}

// ---------------------------------------------------------------------------
extern "C" void kernel_launch(void* const* d_in, const int* in_sizes, int n_in,
                              void* d_out, int out_size, void* d_ws, size_t ws_size,
                              hipStream_t stream)
{
    const float* query = (const float*)d_in[0];
    const float* refp  = (const float*)d_in[1];
    const float* v0    = (const float*)d_in[2];
    const float* v1    = (const float*)d_in[3];
    const float* v2    = (const float*)d_in[4];
    const float* Wv    = (const float*)d_in[5];
    const float* bv    = (const float*)d_in[6];
    const float* Ws    = (const float*)d_in[7];
    const float* bs    = (const float*)d_in[8];
    const float* Wa    = (const float*)d_in[9];
    const float* ba    = (const float*)d_in[10];
    const float* Wo    = (const float*)d_in[11];
    const float* bo    = (const float*)d_in[12];
    float* out = (float*)d_out;

    char* wsb = (char*)d_ws;
    u16*   proj  = (u16*)wsb;    wsb += (size_t)B_ * P_ * 256 * 2;   // 13.44 MB
    float* S     = (float*)wsb;  wsb += (size_t)B_ * NQ_ * 288 * 4;  // 23.04 MB
    u16*   Vt    = (u16*)wsb;    wsb += (size_t)B_ * P_ * 256 * 2;   // 13.44 MB
    u16*   out2  = (u16*)wsb;    wsb += (size_t)B_ * NQ_ * 256 * 2;  // 10.24 MB
    u16*   wb    = (u16*)wsb;    wsb += (size_t)204800 * 2;          // 0.4 MB
    u16* Wvb = wb;
    u16* Wsb = wb + 65536;
    u16* Wab = wb + 114688;
    u16* Wob = wb + 139264;

    dim3 blk(256);

    // 0a) weights f32 -> bf16 (one launch, 25600 chunks of 8)
    cvt_weights<<<dim3(100), blk, 0, stream>>>(Wv, Ws, Wa, Wo, wb);

    // 0b) value transpose+cvt -> Vt bf16 [b][pixel][c]
    transpose_value<<<dim3(157, 4, 6), blk, 0, stream>>>(v0, v1, v2, Vt);

    // 1) value projection -> proj bf16.  nRowTiles=206, npanel=4 -> 26*4*8
    gemm_panel<false, u16><<<dim3(832), blk, 0, stream>>>(
        Vt, B_ * P_, 206, 4, Wvb, bv, 256, Wvb, bv, 256, proj);

    // 2) offsets+logits -> S f32 (A = query f32, inline cvt).  157 tiles, 5 panels
    gemm_panel<true, float><<<dim3(800), blk, 0, stream>>>(
        query, B_ * NQ_, 157, 5, Wsb, bs, 192, Wab, ba, 288, S);

    // 3) softmax + bilinear sampling -> out2 bf16 (2 queries / block)
    sample_kernel<<<dim3(NQ_), blk, 0, stream>>>(S, refp, proj, out2);

    // 4) output projection -> d_out f32.  nRowTiles=157, npanel=4 -> 20*4*8
    gemm_panel<false, float><<<dim3(640), blk, 0, stream>>>(
        out2, B_ * NQ_, 157, 4, Wob, bo, 256, Wob, bo, 256, out);
}